// Round 1
// baseline (3306.929 us; speedup 1.0000x reference)
//
#include <hip/hip_runtime.h>
#include <math.h>

#define NTOK   16384      // B*S = 8*2048
#define DDIM   1024
#define HDIM   128
#define NEXP   32
#define NROUTE 30
#define TOPK   4
#define TS     64         // token slots per block
#define BK     64         // K-chunk for GEMM1
#define BD     64         // D-chunk for GEMM2

__device__ __forceinline__ float sigmoidf_(float x) { return 1.f / (1.f + expf(-x)); }
__device__ __forceinline__ float siluf_(float x)    { return x / (1.f + expf(-x)); }

// ---------------- router: logits, sigmoid, top-k, counts ----------------
__global__ __launch_bounds__(256) void router_kernel(
    const float* __restrict__ SI,     // selection_input [NTOK][DDIM]
    const float* __restrict__ ES,     // expert_sel [NEXP][DDIM]
    const float* __restrict__ bias,   // [NEXP]
    float* __restrict__ out_sel,      // d_out + NTOK*DDIM, sel as float [NTOK][6]
    float* __restrict__ w6,           // ws: weights [NTOK][6]
    int* __restrict__ sel_e,          // ws: routed indices [NTOK][4]
    int* __restrict__ counts)         // ws: [4][NEXP]
{
  const int wave = threadIdx.x >> 6;
  const int lane = threadIdx.x & 63;
  const int tok0 = blockIdx.x * 32 + wave * 8;
  __shared__ float lg[32][NEXP];

  // X fragments for 8 tokens, 16 f32 per lane (k = u*64 + lane)
  float xr[8][16];
#pragma unroll
  for (int t = 0; t < 8; ++t) {
    const float* xp = SI + (size_t)(tok0 + t) * DDIM + lane;
#pragma unroll
    for (int u = 0; u < 16; ++u) xr[t][u] = xp[u * 64];
  }

  for (int e = 0; e < NEXP; ++e) {
    float es[16];
    const float* ep = ES + (size_t)e * DDIM + lane;
#pragma unroll
    for (int u = 0; u < 16; ++u) es[u] = ep[u * 64];
#pragma unroll
    for (int t = 0; t < 8; ++t) {
      float s = 0.f;
#pragma unroll
      for (int u = 0; u < 16; ++u) s = fmaf(xr[t][u], es[u], s);
#pragma unroll
      for (int off = 32; off > 0; off >>= 1) s += __shfl_xor(s, off, 64);
      if (lane == 0) lg[wave * 8 + t][e] = s;
    }
  }
  __syncthreads();

  if (threadIdx.x < 32) {
    const int tl  = threadIdx.x;
    const int tok = blockIdx.x * 32 + tl;
    float sc[NROUTE];
#pragma unroll
    for (int e = 0; e < NEXP; ++e) {
      const float a = sigmoidf_(lg[tl][e]);
      lg[tl][e] = a;                       // keep affinity for weight lookup
      if (e < NROUTE) sc[e] = a + bias[e]; // biased score picks indices only
    }
    unsigned used = 0u;
    int idx[6];
#pragma unroll
    for (int j = 0; j < TOPK; ++j) {
      float bv = -1e30f; int best = 0;
#pragma unroll
      for (int e = 0; e < NROUTE; ++e) {
        if (!((used >> e) & 1u) && sc[e] > bv) { bv = sc[e]; best = e; }
      }
      used |= (1u << best);
      idx[j] = best;
    }
    idx[4] = 30; idx[5] = 31;
#pragma unroll
    for (int j = 0; j < 6; ++j) {
      out_sel[(size_t)tok * 6 + j] = (float)idx[j];
      w6[(size_t)tok * 6 + j] = lg[tl][idx[j]];
    }
#pragma unroll
    for (int j = 0; j < TOPK; ++j) {
      sel_e[(size_t)tok * TOPK + j] = idx[j];
      atomicAdd(&counts[j * NEXP + idx[j]], 1);
    }
  }
}

// ---------------- exclusive scan of counts -> offsets ----------------
__global__ __launch_bounds__(64) void scan_kernel(const int* __restrict__ counts,
                                                  int* __restrict__ offsets)
{
  const int j = threadIdx.x;
  if (j < TOPK) {
    int run = 0;
    for (int e = 0; e < NEXP; ++e) { offsets[j * NEXP + e] = run; run += counts[j * NEXP + e]; }
  }
}

// ---------------- scatter tokens into per-(rank, expert) lists ----------------
__global__ __launch_bounds__(256) void scatter_kernel(
    const int* __restrict__ sel_e, const float* __restrict__ w6,
    const int* __restrict__ offsets, int* __restrict__ cursor,
    int* __restrict__ list_tok, float* __restrict__ list_w)
{
  const int t = blockIdx.x * 256 + threadIdx.x;
  if (t >= NTOK) return;
#pragma unroll
  for (int j = 0; j < TOPK; ++j) {
    const int e   = sel_e[(size_t)t * TOPK + j];
    const int pos = atomicAdd(&cursor[j * NEXP + e], 1);
    const int dst = j * NTOK + offsets[j * NEXP + e] + pos;
    list_tok[dst] = t;
    list_w[dst]   = w6[(size_t)t * 6 + j];
  }
}

// ---------------- fused expert FFN pass ----------------
// pass 0..3: routed rank j grouped by expert; pass 4/5: shared experts 30/31.
// Each pass touches each token exactly once -> plain RMW of out, no atomics.
__global__ __launch_bounds__(256) void ffn_pass_kernel(
    const float* __restrict__ X, const float* __restrict__ keys,
    const float* __restrict__ values, const float* __restrict__ w6,
    const int* __restrict__ counts, const int* __restrict__ offsets,
    const int* __restrict__ list_tok, const float* __restrict__ list_w,
    float* __restrict__ out, const int pass)
{
  int e, n, base;
  if (pass >= TOPK) { e = NROUTE + (pass - TOPK); n = NTOK; base = 0; }
  else {
    e = blockIdx.y;
    n = counts[pass * NEXP + e];
    base = pass * NTOK + offsets[pass * NEXP + e];
  }
  const int row0 = blockIdx.x * TS;
  if (row0 >= n) return;
  const int nrow = min(TS, n - row0);
  const int tid = threadIdx.x;

  __shared__ int   s_tok[TS];
  __shared__ float s_w[TS];
  __shared__ float Xs[BK][TS + 4];      // X^T tile  [k][slot]
  __shared__ float Ks[BK][HDIM + 4];    // keys tile [k][h]
  __shared__ float Hs[TS][HDIM + 4];    // silu(h)   [slot][h]
  __shared__ float Vs[HDIM][BD + 4];    // values    [h][d]

  if (tid < TS) {
    int t = 0; float w = 0.f;
    if (tid < nrow) {
      if (pass >= TOPK) { t = row0 + tid; w = w6[(size_t)t * 6 + pass]; }
      else { t = list_tok[base + row0 + tid]; w = list_w[base + row0 + tid]; }
    }
    s_tok[tid] = t; s_w[tid] = w;
  }

  const int tx = tid & 15;   // N dimension (h then d), contiguous for coalescing
  const int ty = tid >> 4;   // slot dimension

  float acc1[4][8];
#pragma unroll
  for (int i = 0; i < 4; ++i)
#pragma unroll
    for (int j = 0; j < 8; ++j) acc1[i][j] = 0.f;

  const float* kmat = keys + (size_t)e * DDIM * HDIM;

  // ---- GEMM1: H[slot][h] = X[slot][:] @ keys[e][:, h] ----
  for (int kc = 0; kc < DDIM; kc += BK) {
    __syncthreads();
    {
      const int slot = tid >> 2, q = tid & 3;
      const float4* xr = (const float4*)(X + (size_t)s_tok[slot] * DDIM + kc);
#pragma unroll
      for (int u = 0; u < 4; ++u) {
        const float4 v = xr[q * 4 + u];
        const int k = (q * 4 + u) * 4;
        Xs[k + 0][slot] = v.x; Xs[k + 1][slot] = v.y;
        Xs[k + 2][slot] = v.z; Xs[k + 3][slot] = v.w;
      }
    }
    {
      const float4* kb = (const float4*)(kmat + (size_t)kc * HDIM);
#pragma unroll
      for (int u = 0; u < 8; ++u) {
        const int flat = tid + u * 256;
        const int k = flat >> 5, h4 = flat & 31;
        *(float4*)&Ks[k][h4 * 4] = kb[(size_t)k * 32 + h4];
      }
    }
    __syncthreads();
#pragma unroll 4
    for (int k = 0; k < BK; ++k) {
      const float4 xv = *(const float4*)&Xs[k][ty * 4];
      const float4 k0 = *(const float4*)&Ks[k][tx * 8];
      const float4 k1 = *(const float4*)&Ks[k][tx * 8 + 4];
      const float xa[4] = {xv.x, xv.y, xv.z, xv.w};
      const float kk[8] = {k0.x, k0.y, k0.z, k0.w, k1.x, k1.y, k1.z, k1.w};
#pragma unroll
      for (int i = 0; i < 4; ++i)
#pragma unroll
        for (int j = 0; j < 8; ++j) acc1[i][j] = fmaf(xa[i], kk[j], acc1[i][j]);
    }
  }

  // silu -> Hs
#pragma unroll
  for (int i = 0; i < 4; ++i) {
    float4 a, b;
    a.x = siluf_(acc1[i][0]); a.y = siluf_(acc1[i][1]);
    a.z = siluf_(acc1[i][2]); a.w = siluf_(acc1[i][3]);
    b.x = siluf_(acc1[i][4]); b.y = siluf_(acc1[i][5]);
    b.z = siluf_(acc1[i][6]); b.w = siluf_(acc1[i][7]);
    *(float4*)&Hs[ty * 4 + i][tx * 8]     = a;
    *(float4*)&Hs[ty * 4 + i][tx * 8 + 4] = b;
  }

  // ---- GEMM2: out[tok][d] (+)= w * (Hs[slot][:] @ values[e][:, d]) ----
  const float* vmat = values + (size_t)e * HDIM * DDIM;
  for (int dc = 0; dc < DDIM; dc += BD) {
    __syncthreads();
    {
#pragma unroll
      for (int u = 0; u < 8; ++u) {
        const int flat = tid + u * 256;
        const int h = flat >> 4, d4 = flat & 15;
        *(float4*)&Vs[h][d4 * 4] = *(const float4*)(vmat + (size_t)h * DDIM + dc + d4 * 4);
      }
    }
    __syncthreads();
    float acc2[4][4];
#pragma unroll
    for (int i = 0; i < 4; ++i)
#pragma unroll
      for (int j = 0; j < 4; ++j) acc2[i][j] = 0.f;

#pragma unroll 4
    for (int h = 0; h < HDIM; ++h) {
      const float4 vv = *(const float4*)&Vs[h][tx * 4];
      const float va[4] = {vv.x, vv.y, vv.z, vv.w};
      float hv[4];
#pragma unroll
      for (int i = 0; i < 4; ++i) hv[i] = Hs[ty * 4 + i][h];
#pragma unroll
      for (int i = 0; i < 4; ++i)
#pragma unroll
        for (int j = 0; j < 4; ++j) acc2[i][j] = fmaf(hv[i], va[j], acc2[i][j]);
    }
#pragma unroll
    for (int i = 0; i < 4; ++i) {
      const int slot = ty * 4 + i;
      if (slot < nrow) {
        const float w = s_w[slot];
        float* op = out + (size_t)s_tok[slot] * DDIM + dc + tx * 4;
        float4 r;
        r.x = acc2[i][0] * w; r.y = acc2[i][1] * w;
        r.z = acc2[i][2] * w; r.w = acc2[i][3] * w;
        if (pass != 0) {
          const float4 o = *(const float4*)op;
          r.x += o.x; r.y += o.y; r.z += o.z; r.w += o.w;
        }
        *(float4*)op = r;
      }
    }
  }
}

extern "C" void kernel_launch(void* const* d_in, const int* in_sizes, int n_in,
                              void* d_out, int out_size, void* d_ws, size_t ws_size,
                              hipStream_t stream)
{
  const float* X    = (const float*)d_in[0];   // token_stream
  const float* SI   = (const float*)d_in[1];   // selection_input
  const float* keys = (const float*)d_in[2];   // [E][D][H]
  const float* vals = (const float*)d_in[3];   // [E][H][D]
  const float* ES   = (const float*)d_in[4];   // [E][D]
  const float* bias = (const float*)d_in[5];   // [E]
  float* out = (float*)d_out;
  float* out_sel = out + (size_t)NTOK * DDIM;  // sel chunk, written as float

  char* ws = (char*)d_ws;
  int*   counts   = (int*)(ws + 0);            // [4][32]
  int*   cursor   = (int*)(ws + 512);          // [4][32]
  int*   offsets  = (int*)(ws + 1024);         // [4][32]
  int*   sel_e    = (int*)(ws + 2048);                                        // [NTOK][4]
  float* w6       = (float*)(ws + 2048 + (size_t)NTOK * TOPK * 4);            // [NTOK][6]
  int*   list_tok = (int*)(ws + 2048 + (size_t)NTOK * (TOPK + 6) * 4);        // [4][NTOK]
  float* list_w   = (float*)(ws + 2048 + (size_t)NTOK * (TOPK + 6 + TOPK) * 4); // [4][NTOK]

  hipMemsetAsync(counts, 0, 1024, stream);     // counts + cursor

  router_kernel<<<NTOK / 32, 256, 0, stream>>>(SI, ES, bias, out_sel, w6, sel_e, counts);
  scan_kernel<<<1, 64, 0, stream>>>(counts, offsets);
  scatter_kernel<<<NTOK / 256, 256, 0, stream>>>(sel_e, w6, offsets, cursor, list_tok, list_w);

  for (int pass = 0; pass < 6; ++pass) {
    dim3 grid(NTOK / TS, pass < TOPK ? NEXP : 1, 1);
    ffn_pass_kernel<<<grid, 256, 0, stream>>>(X, keys, vals, w6, counts, offsets,
                                              list_tok, list_w, out, pass);
  }
}

// Round 2
// 1207.411 us; speedup vs baseline: 2.7389x; 2.7389x over previous
//
#include <hip/hip_runtime.h>
#include <math.h>

#define NTOK   16384      // B*S = 8*2048
#define DDIM   1024
#define HDIM   128
#define NEXP   32
#define NROUTE 30
#define TOPK   4
#define TS     64         // token slots per FFN block

typedef short bf16x8 __attribute__((ext_vector_type(8)));
typedef float f32x16 __attribute__((ext_vector_type(16)));

__device__ __forceinline__ float sigmoidf_(float x) { return 1.f / (1.f + expf(-x)); }

// round-to-nearest-even fp32 -> bf16 (bit pattern)
__device__ __forceinline__ unsigned short f2bf(float x) {
  unsigned u = __float_as_uint(x);
  u += 0x7fffu + ((u >> 16) & 1u);
  return (unsigned short)(u >> 16);
}

__device__ __forceinline__ f32x16 mfma32(uint4 a, uint4 b, f32x16 c) {
  union { uint4 u; bf16x8 h; } A, B;
  A.u = a; B.u = b;
  return __builtin_amdgcn_mfma_f32_32x32x16_bf16(A.h, B.h, c, 0, 0, 0);
}

__device__ __forceinline__ void gload16(const void* g, void* l) {
  __builtin_amdgcn_global_load_lds(
      (const __attribute__((address_space(1))) unsigned int*)g,
      (__attribute__((address_space(3))) unsigned int*)l, 16, 0, 0);
}

// ---------------- prep: X fp32 -> bf16 (same layout) ----------------
__global__ __launch_bounds__(256) void cvt_x_kernel(const float* __restrict__ X,
                                                    unsigned short* __restrict__ Xb)
{
  const size_t base = ((size_t)blockIdx.x * 256 + threadIdx.x) * 16;
  unsigned short v[16];
#pragma unroll
  for (int i = 0; i < 4; ++i) {
    const float4 f = *(const float4*)(X + base + i * 4);
    v[i * 4 + 0] = f2bf(f.x); v[i * 4 + 1] = f2bf(f.y);
    v[i * 4 + 2] = f2bf(f.z); v[i * 4 + 3] = f2bf(f.w);
  }
  *(uint4*)(Xb + base) = *(const uint4*)v;
  *(uint4*)(Xb + base + 8) = *(const uint4*)(v + 8);
}

// ---------------- prep: keys [E][D][H] -> Kt bf16 [E][H][D] ----------------
__global__ __launch_bounds__(256) void tr_keys_kernel(const float* __restrict__ K,
                                                      unsigned short* __restrict__ Kt)
{
  __shared__ float t[64][129];
  const int e = blockIdx.y, d0 = blockIdx.x * 64;
  const float* src = K + ((size_t)e * DDIM + d0) * HDIM;
#pragma unroll
  for (int u = 0; u < 32; ++u) {
    const int f = threadIdx.x + u * 256;
    t[f >> 7][f & 127] = src[f];
  }
  __syncthreads();
  unsigned short* dst = Kt + (size_t)e * HDIM * DDIM + d0;
#pragma unroll
  for (int u = 0; u < 32; ++u) {
    const int f = threadIdx.x + u * 256;
    const int h = f >> 6, d = f & 63;
    dst[(size_t)h * DDIM + d] = f2bf(t[d][h]);
  }
}

// ---------------- prep: values [E][H][D] -> Vt bf16 [E][D][H] ----------------
__global__ __launch_bounds__(256) void tr_vals_kernel(const float* __restrict__ V,
                                                      unsigned short* __restrict__ Vt)
{
  __shared__ float t[128][65];
  const int e = blockIdx.y, d0 = blockIdx.x * 64;
  const float* src = V + (size_t)e * HDIM * DDIM + d0;
#pragma unroll
  for (int u = 0; u < 32; ++u) {
    const int f = threadIdx.x + u * 256;
    const int h = f >> 6, d = f & 63;
    t[h][d] = src[(size_t)h * DDIM + d];
  }
  __syncthreads();
  unsigned short* dst = Vt + ((size_t)e * DDIM + d0) * HDIM;
#pragma unroll
  for (int u = 0; u < 32; ++u) {
    const int f = threadIdx.x + u * 256;
    const int d = f >> 7, h = f & 127;
    dst[(size_t)d * HDIM + h] = f2bf(t[h][d]);
  }
}

// ---------------- router: logits, sigmoid, top-k, counts ----------------
__global__ __launch_bounds__(256) void router_kernel(
    const float* __restrict__ SI, const float* __restrict__ ES,
    const float* __restrict__ bias, float* __restrict__ out_sel,
    float* __restrict__ w6, int* __restrict__ sel_e, int* __restrict__ counts)
{
  const int wave = threadIdx.x >> 6;
  const int lane = threadIdx.x & 63;
  const int tok0 = blockIdx.x * 32 + wave * 8;
  __shared__ float lg[32][NEXP];

  float xr[8][16];
#pragma unroll
  for (int t = 0; t < 8; ++t) {
    const float* xp = SI + (size_t)(tok0 + t) * DDIM + lane;
#pragma unroll
    for (int u = 0; u < 16; ++u) xr[t][u] = xp[u * 64];
  }

  for (int e = 0; e < NEXP; ++e) {
    float es[16];
    const float* ep = ES + (size_t)e * DDIM + lane;
#pragma unroll
    for (int u = 0; u < 16; ++u) es[u] = ep[u * 64];
#pragma unroll
    for (int t = 0; t < 8; ++t) {
      float s = 0.f;
#pragma unroll
      for (int u = 0; u < 16; ++u) s = fmaf(xr[t][u], es[u], s);
#pragma unroll
      for (int off = 32; off > 0; off >>= 1) s += __shfl_xor(s, off, 64);
      if (lane == 0) lg[wave * 8 + t][e] = s;
    }
  }
  __syncthreads();

  if (threadIdx.x < 32) {
    const int tl  = threadIdx.x;
    const int tok = blockIdx.x * 32 + tl;
    float sc[NROUTE];
#pragma unroll
    for (int e = 0; e < NEXP; ++e) {
      const float a = sigmoidf_(lg[tl][e]);
      lg[tl][e] = a;
      if (e < NROUTE) sc[e] = a + bias[e];
    }
    unsigned used = 0u;
    int idx[6];
#pragma unroll
    for (int j = 0; j < TOPK; ++j) {
      float bv = -1e30f; int best = 0;
#pragma unroll
      for (int e = 0; e < NROUTE; ++e)
        if (!((used >> e) & 1u) && sc[e] > bv) { bv = sc[e]; best = e; }
      used |= (1u << best);
      idx[j] = best;
    }
    idx[4] = 30; idx[5] = 31;
#pragma unroll
    for (int j = 0; j < 6; ++j) {
      out_sel[(size_t)tok * 6 + j] = (float)idx[j];
      w6[(size_t)tok * 6 + j] = lg[tl][idx[j]];
    }
#pragma unroll
    for (int j = 0; j < TOPK; ++j) {
      sel_e[(size_t)tok * TOPK + j] = idx[j];
      atomicAdd(&counts[j * NEXP + idx[j]], 1);
    }
  }
}

__global__ __launch_bounds__(64) void scan_kernel(const int* __restrict__ counts,
                                                  int* __restrict__ offsets)
{
  const int j = threadIdx.x;
  if (j < TOPK) {
    int run = 0;
    for (int e = 0; e < NEXP; ++e) { offsets[j * NEXP + e] = run; run += counts[j * NEXP + e]; }
  }
}

__global__ __launch_bounds__(256) void scatter_kernel(
    const int* __restrict__ sel_e, const float* __restrict__ w6,
    const int* __restrict__ offsets, int* __restrict__ cursor,
    int* __restrict__ list_tok, float* __restrict__ list_w)
{
  const int t = blockIdx.x * 256 + threadIdx.x;
  if (t >= NTOK) return;
#pragma unroll
  for (int j = 0; j < TOPK; ++j) {
    const int e   = sel_e[(size_t)t * TOPK + j];
    const int pos = atomicAdd(&cursor[j * NEXP + e], 1);
    const int dst = j * NTOK + offsets[j * NEXP + e] + pos;
    list_tok[dst] = t;
    list_w[dst]   = w6[(size_t)t * 6 + j];
  }
}

// ---------------- fused MFMA FFN pass ----------------
// pass 0..3: routed rank grouped by expert; pass 4/5: shared experts 30/31.
// Each pass touches each token at most once -> plain RMW of out (pass 0 writes).
// LDS 48KB: [0,16K) Xs then Hs (aliased), [16K,48K) Kts then Vts (aliased).
// Row stride 256B; 16B slots XOR-swizzled by (row&7) (write side = pre-swizzled
// global source for global_load_lds; read side applies same XOR).
__global__ __launch_bounds__(256) void ffn_mfma_kernel(
    const unsigned short* __restrict__ Xb, const unsigned short* __restrict__ Kt,
    const unsigned short* __restrict__ Vt, const float* __restrict__ w6,
    const int* __restrict__ counts, const int* __restrict__ offsets,
    const int* __restrict__ list_tok, const float* __restrict__ list_w,
    float* __restrict__ out, const int pass)
{
  __shared__ char lds[49152];
  __shared__ int   s_tok[TS];
  __shared__ float s_w[TS];

  int e, n, base;
  if (pass >= TOPK) { e = NROUTE + (pass - TOPK); n = NTOK; base = 0; }
  else {
    e = blockIdx.y;
    n = counts[pass * NEXP + e];
    base = pass * NTOK + offsets[pass * NEXP + e];
  }
  const int row0 = blockIdx.x * TS;
  if (row0 >= n) return;
  const int nrow = min(TS, n - row0);
  const int tid = threadIdx.x;

  if (tid < TS) {
    int t = 0; float w = 0.f;
    if (tid < nrow) {
      if (pass >= TOPK) { t = row0 + tid; w = w6[(size_t)t * 6 + pass]; }
      else { t = list_tok[base + row0 + tid]; w = list_w[base + row0 + tid]; }
    }
    s_tok[tid] = t; s_w[tid] = w;
  }
  __syncthreads();

  const int wid   = tid >> 6, lane = tid & 63;
  const int wm    = wid >> 1, wn   = wid & 1;
  const int lrow  = lane & 31, khalf = lane >> 5;
  const int l16   = lane & 15, lq    = lane >> 4;

  char* Xs  = lds;           // [64 rows][256 B]
  char* Kts = lds + 16384;   // [128 rows][256 B]
  char* Hs  = lds;           // alias Xs after GEMM1
  char* Vts = lds + 16384;   // alias Kts after GEMM1

  // staging source pointers (pre-swizzled global addresses)
  const unsigned short* xsrc[4];
#pragma unroll
  for (int u = 0; u < 4; ++u) {
    const int row = (wid * 4 + u) * 4 + lq;
    xsrc[u] = Xb + (size_t)s_tok[row] * DDIM + (size_t)((l16 ^ (row & 7)) * 8);
  }
  const unsigned short* ksrc[8];
#pragma unroll
  for (int u = 0; u < 8; ++u) {
    const int h = (wid * 8 + u) * 4 + lq;
    ksrc[u] = Kt + ((size_t)e * HDIM + h) * DDIM + (size_t)((l16 ^ (h & 7)) * 8);
  }

  f32x16 acc0, acc1;
#pragma unroll
  for (int i = 0; i < 16; ++i) { acc0[i] = 0.f; acc1[i] = 0.f; }

  const int arow = wm * 32 + lrow;
  const int h0 = wn * 64 + lrow, h1 = h0 + 32;

  // ---- GEMM1: Hs[64][128] = Xb[tok] @ keys[e]  (A=Xs, B=Kts) ----
  for (int kc = 0; kc < DDIM; kc += 128) {
    __syncthreads();
#pragma unroll
    for (int u = 0; u < 4; ++u) gload16(xsrc[u] + kc, Xs + (wid * 4 + u) * 1024);
#pragma unroll
    for (int u = 0; u < 8; ++u) gload16(ksrc[u] + kc, Kts + (wid * 8 + u) * 1024);
    asm volatile("s_waitcnt vmcnt(0)" ::: "memory");
    __syncthreads();
#pragma unroll
    for (int ks = 0; ks < 8; ++ks) {
      const int slot = ks * 2 + khalf;
      const uint4 av  = *(const uint4*)(Xs  + arow * 256 + ((slot ^ (arow & 7)) << 4));
      const uint4 bv0 = *(const uint4*)(Kts + h0 * 256   + ((slot ^ (h0 & 7)) << 4));
      const uint4 bv1 = *(const uint4*)(Kts + h1 * 256   + ((slot ^ (h1 & 7)) << 4));
      acc0 = mfma32(av, bv0, acc0);
      acc1 = mfma32(av, bv1, acc1);
    }
  }
  __syncthreads();   // everyone done reading Xs/Kts

  // silu * w -> Hs (bf16, swizzled)
#pragma unroll
  for (int nt = 0; nt < 2; ++nt) {
    const f32x16 a = nt ? acc1 : acc0;
    const int hcol = wn * 64 + nt * 32 + lrow;
#pragma unroll
    for (int r = 0; r < 16; ++r) {
      const int row = wm * 32 + (r & 3) + 8 * (r >> 2) + 4 * khalf;
      float v = a[r];
      v = v / (1.f + expf(-v)) * s_w[row];
      *(unsigned short*)(Hs + row * 256 + ((hcol * 2) ^ ((row & 7) << 4))) = f2bf(v);
    }
  }
  __syncthreads();

  // ---- GEMM2: out[tok][1024] (+)= Hs @ values[e]  (A=Hs, B=Vts) ----
  const unsigned short* vsrc[8];
  int vrow[8];
#pragma unroll
  for (int u = 0; u < 8; ++u) {
    const int d = (wid * 8 + u) * 4 + lq;
    vrow[u] = d;
    vsrc[u] = Vt + ((size_t)e * DDIM + d) * HDIM + (size_t)((l16 ^ (d & 7)) * 8);
  }

  for (int dc = 0; dc < 8; ++dc) {
#pragma unroll
    for (int u = 0; u < 8; ++u)
      gload16(vsrc[u] + (size_t)dc * 128 * HDIM, Vts + (wid * 8 + u) * 1024);
    asm volatile("s_waitcnt vmcnt(0)" ::: "memory");
    __syncthreads();

    f32x16 o0, o1;
#pragma unroll
    for (int i = 0; i < 16; ++i) { o0[i] = 0.f; o1[i] = 0.f; }
    const int d0 = wn * 64 + lrow, d1 = d0 + 32;
#pragma unroll
    for (int ks = 0; ks < 8; ++ks) {
      const int slot = ks * 2 + khalf;
      const uint4 av  = *(const uint4*)(Hs  + arow * 256 + ((slot ^ (arow & 7)) << 4));
      const uint4 bv0 = *(const uint4*)(Vts + d0 * 256   + ((slot ^ (d0 & 7)) << 4));
      const uint4 bv1 = *(const uint4*)(Vts + d1 * 256   + ((slot ^ (d1 & 7)) << 4));
      o0 = mfma32(av, bv0, o0);
      o1 = mfma32(av, bv1, o1);
    }

#pragma unroll
    for (int nt = 0; nt < 2; ++nt) {
      const f32x16 o = nt ? o1 : o0;
      const int col = dc * 128 + wn * 64 + nt * 32 + lrow;
#pragma unroll
      for (int r = 0; r < 16; ++r) {
        const int row = wm * 32 + (r & 3) + 8 * (r >> 2) + 4 * khalf;
        if (row < nrow) {
          float* op = out + (size_t)s_tok[row] * DDIM + col;
          if (pass == 0) *op = o[r];
          else           *op += o[r];
        }
      }
    }
    __syncthreads();   // Vts reads done before restaging
  }
}

extern "C" void kernel_launch(void* const* d_in, const int* in_sizes, int n_in,
                              void* d_out, int out_size, void* d_ws, size_t ws_size,
                              hipStream_t stream)
{
  const float* X    = (const float*)d_in[0];
  const float* SI   = (const float*)d_in[1];
  const float* keys = (const float*)d_in[2];
  const float* vals = (const float*)d_in[3];
  const float* ES   = (const float*)d_in[4];
  const float* bias = (const float*)d_in[5];
  float* out = (float*)d_out;
  float* out_sel = out + (size_t)NTOK * DDIM;

  char* ws = (char*)d_ws;
  int*   counts   = (int*)(ws + 0);       // [4][32]
  int*   cursor   = (int*)(ws + 512);
  int*   offsets  = (int*)(ws + 1024);
  int*   sel_e    = (int*)(ws + 2048);                    // 256 KB
  float* w6       = (float*)(ws + 264192);                // 384 KB
  int*   list_tok = (int*)(ws + 657408);                  // 256 KB
  float* list_w   = (float*)(ws + 919552);                // 256 KB
  unsigned short* Xb = (unsigned short*)(ws + 1181696);   // 32 MB
  unsigned short* Kt = (unsigned short*)(ws + 34736128);  // 8 MB
  unsigned short* Vt = (unsigned short*)(ws + 43124736);  // 8 MB

  hipMemsetAsync(counts, 0, 1024, stream);

  cvt_x_kernel<<<(NTOK * DDIM) / (256 * 16), 256, 0, stream>>>(X, Xb);
  tr_keys_kernel<<<dim3(DDIM / 64, NEXP), 256, 0, stream>>>(keys, Kt);
  tr_vals_kernel<<<dim3(DDIM / 64, NEXP), 256, 0, stream>>>(vals, Vt);

  router_kernel<<<NTOK / 32, 256, 0, stream>>>(SI, ES, bias, out_sel, w6, sel_e, counts);
  scan_kernel<<<1, 64, 0, stream>>>(counts, offsets);
  scatter_kernel<<<NTOK / 256, 256, 0, stream>>>(sel_e, w6, offsets, cursor, list_tok, list_w);

  for (int pass = 0; pass < 6; ++pass) {
    dim3 grid(NTOK / TS, pass < TOPK ? NROUTE : 1, 1);
    ffn_mfma_kernel<<<grid, 256, 0, stream>>>(Xb, Kt, Vt, w6, counts, offsets,
                                              list_tok, list_w, out, pass);
  }
}

// Round 3
// 705.225 us; speedup vs baseline: 4.6892x; 1.7121x over previous
//
#include <hip/hip_runtime.h>
#include <math.h>

#define NTOK   16384
#define DDIM   1024
#define HDIM   128
#define NEXP   32
#define NROUTE 30
#define TOPK   4
#define TS     32
#define NJOBS  544          // 8*68, >= 512+30 worst case

typedef short bf16x8 __attribute__((ext_vector_type(8)));
typedef float f32x16 __attribute__((ext_vector_type(16)));
typedef unsigned short u16;

__device__ __forceinline__ float sigmoidf_(float x) { return 1.f / (1.f + expf(-x)); }

__device__ __forceinline__ u16 f2bf(float x) {
  unsigned u = __float_as_uint(x);
  u += 0x7fffu + ((u >> 16) & 1u);
  return (u16)(u >> 16);
}
__device__ __forceinline__ float bf2f(u16 v) {
  return __uint_as_float(((unsigned)v) << 16);
}

__device__ __forceinline__ f32x16 mfma32(uint4 a, uint4 b, f32x16 c) {
  union { uint4 u; bf16x8 h; } A, B;
  A.u = a; B.u = b;
  return __builtin_amdgcn_mfma_f32_32x32x16_bf16(A.h, B.h, c, 0, 0, 0);
}

__device__ __forceinline__ void gload16(const void* g, void* l) {
  __builtin_amdgcn_global_load_lds(
      (const __attribute__((address_space(1))) unsigned int*)g,
      (__attribute__((address_space(3))) unsigned int*)l, 16, 0, 0);
}

// ---------------- prep: X fp32 -> bf16 ----------------
__global__ __launch_bounds__(256) void cvt_x_kernel(const float* __restrict__ X,
                                                    u16* __restrict__ Xb)
{
  const size_t base = ((size_t)blockIdx.x * 256 + threadIdx.x) * 16;
  u16 v[16];
#pragma unroll
  for (int i = 0; i < 4; ++i) {
    const float4 f = *(const float4*)(X + base + i * 4);
    v[i*4+0] = f2bf(f.x); v[i*4+1] = f2bf(f.y);
    v[i*4+2] = f2bf(f.z); v[i*4+3] = f2bf(f.w);
  }
  *(uint4*)(Xb + base) = *(const uint4*)v;
  *(uint4*)(Xb + base + 8) = *(const uint4*)(v + 8);
}

// ---- prep: keys [E][D][H] -> Kc[e][kc][r=h][perm-k] bf16, chunk-contiguous ----
__global__ __launch_bounds__(256) void prep_k_kernel(const float* __restrict__ K,
                                                     u16* __restrict__ Kc)
{
  __shared__ float t[128][129];
  const int kc = blockIdx.x, e = blockIdx.y, tid = threadIdx.x;
#pragma unroll
  for (int i = 0; i < 64; ++i) {
    const int g = tid + i * 256;
    const int d = g >> 7, h = g & 127;
    t[d][h] = K[((size_t)e * DDIM + kc * 128 + d) * HDIM + h];
  }
  __syncthreads();
  u16* dst = Kc + ((size_t)e * 8 + kc) * 16384;
#pragma unroll
  for (int i = 0; i < 64; ++i) {
    const int f = tid + i * 256;
    const int r = f >> 7, c = f & 127;
    const int k = (((c >> 3) ^ (r & 15)) << 3) | (c & 7);
    dst[f] = f2bf(t[k][r]);
  }
}

// ---- prep: values [E][H][D] -> Vc[e][dc][r=d][perm-h] bf16 ----
__global__ __launch_bounds__(256) void prep_v_kernel(const float* __restrict__ V,
                                                     u16* __restrict__ Vc)
{
  __shared__ float t[128][129];
  const int dc = blockIdx.x, e = blockIdx.y, tid = threadIdx.x;
#pragma unroll
  for (int i = 0; i < 64; ++i) {
    const int g = tid + i * 256;
    const int h = g >> 7, dl = g & 127;
    t[h][dl] = V[((size_t)e * HDIM + h) * DDIM + dc * 128 + dl];
  }
  __syncthreads();
  u16* dst = Vc + ((size_t)e * 8 + dc) * 16384;
#pragma unroll
  for (int i = 0; i < 64; ++i) {
    const int f = tid + i * 256;
    const int r = f >> 7, c = f & 127;
    const int h = (((c >> 3) ^ (r & 15)) << 3) | (c & 7);
    dst[f] = f2bf(t[h][r]);
  }
}

// ---------------- router ----------------
__global__ __launch_bounds__(256) void router_kernel(
    const float* __restrict__ SI, const float* __restrict__ ES,
    const float* __restrict__ bias, float* __restrict__ out_sel,
    float* __restrict__ w6, int* __restrict__ sel_e, int* __restrict__ counts)
{
  const int wave = threadIdx.x >> 6;
  const int lane = threadIdx.x & 63;
  const int tok0 = blockIdx.x * 32 + wave * 8;
  __shared__ float lg[32][NEXP];

  float xr[8][16];
#pragma unroll
  for (int t = 0; t < 8; ++t) {
    const float* xp = SI + (size_t)(tok0 + t) * DDIM + lane;
#pragma unroll
    for (int u = 0; u < 16; ++u) xr[t][u] = xp[u * 64];
  }
  for (int e = 0; e < NEXP; ++e) {
    float es[16];
    const float* ep = ES + (size_t)e * DDIM + lane;
#pragma unroll
    for (int u = 0; u < 16; ++u) es[u] = ep[u * 64];
#pragma unroll
    for (int t = 0; t < 8; ++t) {
      float s = 0.f;
#pragma unroll
      for (int u = 0; u < 16; ++u) s = fmaf(xr[t][u], es[u], s);
#pragma unroll
      for (int off = 32; off > 0; off >>= 1) s += __shfl_xor(s, off, 64);
      if (lane == 0) lg[wave * 8 + t][e] = s;
    }
  }
  __syncthreads();

  if (threadIdx.x < 32) {
    const int tl  = threadIdx.x;
    const int tok = blockIdx.x * 32 + tl;
    float sc[NROUTE];
#pragma unroll
    for (int e = 0; e < NEXP; ++e) {
      const float a = sigmoidf_(lg[tl][e]);
      lg[tl][e] = a;
      if (e < NROUTE) sc[e] = a + bias[e];
    }
    unsigned used = 0u;
    int idx[6];
#pragma unroll
    for (int j = 0; j < TOPK; ++j) {
      float bv = -1e30f; int best = 0;
#pragma unroll
      for (int e = 0; e < NROUTE; ++e)
        if (!((used >> e) & 1u) && sc[e] > bv) { bv = sc[e]; best = e; }
      used |= (1u << best);
      idx[j] = best;
    }
    idx[4] = 30; idx[5] = 31;
#pragma unroll
    for (int j = 0; j < 6; ++j) {
      out_sel[(size_t)tok * 6 + j] = (float)idx[j];
      w6[(size_t)tok * 6 + j] = lg[tl][idx[j]];
    }
#pragma unroll
    for (int j = 0; j < TOPK; ++j) {
      sel_e[(size_t)tok * TOPK + j] = idx[j];
      atomicAdd(&counts[j * NEXP + idx[j]], 1);
    }
  }
}

// ---------------- scan: offsets + job maps ----------------
__global__ __launch_bounds__(256) void scan_kernel(const int* __restrict__ counts,
                                                   int* __restrict__ offsets,
                                                   int4* __restrict__ jm)
{
  const int tid = threadIdx.x;
  for (int i = tid; i < NJOBS; i += 256) {
    const int4 z = make_int4(0, 0, 0, 0);
    jm[4 * NJOBS + i] = (i < 512) ? make_int4(30, i * 32, 32, 0) : z;
    jm[5 * NJOBS + i] = (i < 512) ? make_int4(31, i * 32, 32, 0) : z;
    jm[0 * NJOBS + i] = z; jm[1 * NJOBS + i] = z;
    jm[2 * NJOBS + i] = z; jm[3 * NJOBS + i] = z;
  }
  __syncthreads();
  const int r = tid >> 6, lane = tid & 63;
  if (lane == 0) {
    int off = 0, joff = 0;
    for (int e = 0; e < NROUTE; ++e) {
      const int c = counts[r * NEXP + e];
      offsets[r * NEXP + e] = off;
      const int nch = (c + 31) >> 5;
      for (int ch = 0; ch < nch; ++ch)
        jm[r * NJOBS + joff + ch] = make_int4(e, off + ch * 32, min(32, c - ch * 32), 0);
      joff += nch; off += c;
    }
  }
}

// ---------------- scatter (ranks 0-3 + shared identity lists 4,5) ----------------
__global__ __launch_bounds__(256) void scatter_kernel(
    const int* __restrict__ sel_e, const float* __restrict__ w6,
    const int* __restrict__ offsets, int* __restrict__ cursor,
    int* __restrict__ list_tok, float* __restrict__ list_w)
{
  const int t = blockIdx.x * 256 + threadIdx.x;
  if (t >= NTOK) return;
#pragma unroll
  for (int j = 0; j < TOPK; ++j) {
    const int e   = sel_e[(size_t)t * TOPK + j];
    const int pos = atomicAdd(&cursor[j * NEXP + e], 1);
    const int dst = j * NTOK + offsets[j * NEXP + e] + pos;
    list_tok[dst] = t;
    list_w[dst]   = w6[(size_t)t * 6 + j];
  }
  list_tok[4 * NTOK + t] = t; list_w[4 * NTOK + t] = w6[(size_t)t * 6 + 4];
  list_tok[5 * NTOK + t] = t; list_w[5 * NTOK + t] = w6[(size_t)t * 6 + 5];
}

// ---------------- fused MFMA FFN pass (uniform; MODE 0=write acc,1=rmw acc,2=final) ----
template<int MODE>
__global__ __launch_bounds__(256) void ffn_pass(
    const u16* __restrict__ Xb, const u16* __restrict__ Kc, const u16* __restrict__ Vc,
    const int4* __restrict__ jm, const int* __restrict__ ltok,
    const float* __restrict__ lw, u16* __restrict__ acc, float* __restrict__ out)
{
  __shared__ __align__(16) u16 XsT[32 * 128];    // 8KB
  __shared__ __align__(16) u16 KsT[128 * 128];   // 32KB (aliased as Vts in GEMM2)
  __shared__ __align__(16) u16 HsT[32 * 128];    // 8KB
  __shared__ int   s_tok[TS];
  __shared__ float s_w[TS];

  const int bid = blockIdx.x;
  const int4 J = jm[(bid & 7) * 68 + (bid >> 3)];   // XCD-bijective job swizzle
  const int nrow = J.z;
  if (nrow == 0) return;
  const int e = J.x, base = J.y;
  const int tid = threadIdx.x;

  if (tid < TS) {
    int t = 0; float w = 0.f;
    if (tid < nrow) { t = ltok[base + tid]; w = lw[base + tid]; }
    s_tok[tid] = t; s_w[tid] = w;
  }
  __syncthreads();

  const int wid = tid >> 6, lane = tid & 63;
  const int l31 = lane & 31, khalf = lane >> 5;
  const int l16s = lane & 15, lq = lane >> 4;
  const int wn = wid;

  // X staging rows (2 per lane) with runtime XOR on src slot
  const int xrow0 = wid * 8 + lq, xrow1 = xrow0 + 4;
  const size_t xo0 = (size_t)s_tok[xrow0] * DDIM + ((l16s ^ (xrow0 & 15)) << 3);
  const size_t xo1 = (size_t)s_tok[xrow1] * DDIM + ((l16s ^ (xrow1 & 15)) << 3);
  const u16* kbase = Kc + (size_t)e * 8 * 16384 + (size_t)(wid * 8) * 512 + lane * 8;
  const u16* vbase = Vc + (size_t)e * 8 * 16384 + (size_t)(wid * 8) * 512 + lane * 8;

  #define STAGE_X(kc_) do { \
    gload16(Xb + xo0 + (kc_) * 128, XsT + (wid * 2 + 0) * 512); \
    gload16(Xb + xo1 + (kc_) * 128, XsT + (wid * 2 + 1) * 512); } while (0)
  #define STAGE_W(ptr_, c_) do { \
    _Pragma("unroll") \
    for (int u_ = 0; u_ < 8; ++u_) \
      gload16((ptr_) + (size_t)(c_) * 16384 + u_ * 512, KsT + (wid * 8 + u_) * 512); } while (0)

  STAGE_X(0);
  STAGE_W(kbase, 0);

  f32x16 accv;
#pragma unroll
  for (int i = 0; i < 16; ++i) accv[i] = 0.f;

  uint4 a[8], b[8];
  const int sxor = l31 & 15;

  // ---- GEMM1: Hs[32][128] = X @ keys[e] ----
  for (int kc = 0; kc < 8; ++kc) {
    __syncthreads();                       // chunk kc resident (vmcnt drained)
#pragma unroll
    for (int s = 0; s < 8; ++s) {
      const int slot = s * 2 + khalf;
      a[s] = *(const uint4*)(XsT + l31 * 128 + ((slot ^ sxor) << 3));
      b[s] = *(const uint4*)(KsT + (wn * 32 + l31) * 128 + ((slot ^ sxor) << 3));
    }
    __syncthreads();                       // reads done; LDS reusable
    if (kc < 7) { STAGE_X(kc + 1); STAGE_W(kbase, kc + 1); }
    else        { STAGE_W(vbase, 0); }     // prefetch V chunk 0
#pragma unroll
    for (int s = 0; s < 8; ++s) accv = mfma32(a[s], b[s], accv);
  }

  // silu * w -> Hs (bf16, swizzled)
#pragma unroll
  for (int r = 0; r < 16; ++r) {
    const int row = (r & 3) + 8 * (r >> 2) + 4 * khalf;
    const int hcol = wn * 32 + l31;
    float v = accv[r];
    v = v / (1.f + expf(-v)) * s_w[row];
    HsT[row * 128 + ((((hcol >> 3) ^ (row & 15)) << 3) | (hcol & 7))] = f2bf(v);
  }
  __syncthreads();                          // Hs visible; V chunk 0 resident

  // hoist GEMM2 A fragments (Hs rows fixed)
#pragma unroll
  for (int s = 0; s < 8; ++s) {
    const int slot = s * 2 + khalf;
    a[s] = *(const uint4*)(HsT + l31 * 128 + ((slot ^ sxor) << 3));
  }

  // epilogue row bookkeeping
  unsigned obase[16]; bool oval[16];
#pragma unroll
  for (int r = 0; r < 16; ++r) {
    const int row = (r & 3) + 8 * (r >> 2) + 4 * khalf;
    oval[r] = row < nrow;
    obase[r] = (unsigned)s_tok[row] * DDIM;
  }

  // ---- GEMM2: out (+)= Hs @ values[e] ----
  for (int dc = 0; dc < 8; ++dc) {
#pragma unroll
    for (int s = 0; s < 8; ++s) {
      const int slot = s * 2 + khalf;
      b[s] = *(const uint4*)(KsT + (wn * 32 + l31) * 128 + ((slot ^ sxor) << 3));
    }
    __syncthreads();                        // B reads done
    if (dc < 7) STAGE_W(vbase, dc + 1);
    f32x16 o;
#pragma unroll
    for (int i = 0; i < 16; ++i) o[i] = 0.f;
#pragma unroll
    for (int s = 0; s < 8; ++s) o = mfma32(a[s], b[s], o);

    const int col = dc * 128 + wn * 32 + l31;
#pragma unroll
    for (int r = 0; r < 16; ++r) {
      if (oval[r]) {
        const size_t p = (size_t)obase[r] + col;
        if (MODE == 0)      acc[p] = f2bf(o[r]);
        else if (MODE == 1) acc[p] = f2bf(bf2f(acc[p]) + o[r]);
        else                out[p] = bf2f(acc[p]) + o[r];
      }
    }
    if (dc < 7) __syncthreads();            // next V chunk resident
  }
  #undef STAGE_X
  #undef STAGE_W
}

extern "C" void kernel_launch(void* const* d_in, const int* in_sizes, int n_in,
                              void* d_out, int out_size, void* d_ws, size_t ws_size,
                              hipStream_t stream)
{
  const float* X    = (const float*)d_in[0];
  const float* SI   = (const float*)d_in[1];
  const float* keys = (const float*)d_in[2];
  const float* vals = (const float*)d_in[3];
  const float* ES   = (const float*)d_in[4];
  const float* bias = (const float*)d_in[5];
  float* out = (float*)d_out;
  float* out_sel = out + (size_t)NTOK * DDIM;

  char* ws = (char*)d_ws;
  int*   counts   = (int*)(ws + 0);
  int*   cursor   = (int*)(ws + 512);
  int*   offsets  = (int*)(ws + 1024);
  int4*  jm       = (int4*)(ws + 2048);                 // 6*544*16 = 52224
  int*   list_tok = (int*)(ws + 57344);                 // 6*NTOK int
  float* list_w   = (float*)(ws + 450560);              // 6*NTOK float
  float* w6       = (float*)(ws + 843776);              // NTOK*6
  int*   sel_e    = (int*)(ws + 1236992);               // NTOK*4
  u16*   Xb       = (u16*)(ws + 1507328);               // 32MB
  u16*   Kc       = (u16*)(ws + 35061760);              // 8MB
  u16*   Vc       = (u16*)(ws + 43450368);              // 8MB
  u16*   acc      = (u16*)(ws + 51838976);              // 32MB

  hipMemsetAsync(counts, 0, 1024, stream);              // counts + cursor

  cvt_x_kernel<<<(NTOK * DDIM) / (256 * 16), 256, 0, stream>>>(X, Xb);
  prep_k_kernel<<<dim3(8, NEXP), 256, 0, stream>>>(keys, Kc);
  prep_v_kernel<<<dim3(8, NEXP), 256, 0, stream>>>(vals, Vc);

  router_kernel<<<NTOK / 32, 256, 0, stream>>>(SI, ES, bias, out_sel, w6, sel_e, counts);
  scan_kernel<<<1, 256, 0, stream>>>(counts, offsets, jm);
  scatter_kernel<<<NTOK / 256, 256, 0, stream>>>(sel_e, w6, offsets, cursor, list_tok, list_w);

  // pass order: e30 (write) -> e31, rank0, rank1, rank2 (rmw) -> rank3 (final fp32)
  ffn_pass<0><<<NJOBS, 256, 0, stream>>>(Xb, Kc, Vc, jm + 4 * NJOBS,
      list_tok + 4 * NTOK, list_w + 4 * NTOK, acc, out);
  ffn_pass<1><<<NJOBS, 256, 0, stream>>>(Xb, Kc, Vc, jm + 5 * NJOBS,
      list_tok + 5 * NTOK, list_w + 5 * NTOK, acc, out);
  ffn_pass<1><<<NJOBS, 256, 0, stream>>>(Xb, Kc, Vc, jm + 0 * NJOBS,
      list_tok + 0 * NTOK, list_w + 0 * NTOK, acc, out);
  ffn_pass<1><<<NJOBS, 256, 0, stream>>>(Xb, Kc, Vc, jm + 1 * NJOBS,
      list_tok + 1 * NTOK, list_w + 1 * NTOK, acc, out);
  ffn_pass<1><<<NJOBS, 256, 0, stream>>>(Xb, Kc, Vc, jm + 2 * NJOBS,
      list_tok + 2 * NTOK, list_w + 2 * NTOK, acc, out);
  ffn_pass<2><<<NJOBS, 256, 0, stream>>>(Xb, Kc, Vc, jm + 3 * NJOBS,
      list_tok + 3 * NTOK, list_w + 3 * NTOK, acc, out);
}